// Round 1
// baseline (91.688 us; speedup 1.0000x reference)
//
#include <hip/hip_runtime.h>
#include <stdint.h>

#define NB 4
#define NT 2048
#define NC 1024
#define NH 64
#define NM (NB*NT)

typedef unsigned short u16;
typedef __bf16 bf16_t;
typedef float f32x4 __attribute__((ext_vector_type(4)));
typedef bf16_t bf16x8 __attribute__((ext_vector_type(8)));
typedef u16 u16x8 __attribute__((ext_vector_type(8)));
typedef u16 u16x4 __attribute__((ext_vector_type(4)));

__device__ __forceinline__ u16 f2b(float f) {
  return __builtin_bit_cast(u16, (bf16_t)f);
}

// ---------------- Wq/Wk/Wv [1024][64] f32 -> WT [3][64][1024] bf16 (transposed)
__global__ __launch_bounds__(256) void wt_kernel(const float* __restrict__ Wq,
                                                 const float* __restrict__ Wk,
                                                 const float* __restrict__ Wv,
                                                 u16* __restrict__ wt) {
  const int m = blockIdx.x >> 6;
  const int n = blockIdx.x & 63;
  const float* W = (m == 0) ? Wq : (m == 1) ? Wk : Wv;
  u16* dst = wt + ((size_t)(m * 64 + n)) * NC;
  for (int k = threadIdx.x; k < NC; k += 256) {
    dst[k] = f2b(W[(size_t)k * NH + n]);
  }
}

// ---------------- fused QKV projection: x[8192][1024] f32 @ WT -> q,k bf16 [8192][64], vt bf16 [4][64][2048]
__global__ __launch_bounds__(128) void proj_kernel(const float* __restrict__ x,
                                                   const u16* __restrict__ wt,
                                                   u16* __restrict__ qo,
                                                   u16* __restrict__ ko,
                                                   u16* __restrict__ vto) {
  __shared__ u16 sA[32 * 64];    // [row][k] bf16, 16B-chunk XOR swizzle (chunk ^ row&7)
  __shared__ u16 sB[192 * 64];   // [n][k] bf16, same swizzle
  const int tid = threadIdx.x;
  const int lane = tid & 63;
  const int w = tid >> 6;
  const int g = lane >> 4;
  const int li = lane & 15;
  const int row0 = blockIdx.x * 32;

  const f32x4 zero = {0.f, 0.f, 0.f, 0.f};
  f32x4 acc[12];
  #pragma unroll
  for (int i = 0; i < 12; ++i) acc[i] = zero;

  const int r = tid >> 2;        // 0..31 staging row
  const int fc = tid & 3;        // 16-float chunk within row
  const float* xsrc = x + (size_t)(row0 + r) * NC + fc * 16;

  for (int kt = 0; kt < 16; ++kt) {
    const int k0 = kt * 64;
    // stage A: 32x64 fp32 -> bf16 (coalesced 64B/thread)
    {
      const float4 f0 = *(const float4*)(xsrc + k0);
      const float4 f1 = *(const float4*)(xsrc + k0 + 4);
      const float4 f2 = *(const float4*)(xsrc + k0 + 8);
      const float4 f3 = *(const float4*)(xsrc + k0 + 12);
      u16x8 u0, u1;
      u0[0]=f2b(f0.x); u0[1]=f2b(f0.y); u0[2]=f2b(f0.z); u0[3]=f2b(f0.w);
      u0[4]=f2b(f1.x); u0[5]=f2b(f1.y); u0[6]=f2b(f1.z); u0[7]=f2b(f1.w);
      u1[0]=f2b(f2.x); u1[1]=f2b(f2.y); u1[2]=f2b(f2.z); u1[3]=f2b(f2.w);
      u1[4]=f2b(f3.x); u1[5]=f2b(f3.y); u1[6]=f2b(f3.z); u1[7]=f2b(f3.w);
      const int c0 = fc * 2;
      *(u16x8*)&sA[r * 64 + ((c0 ^ (r & 7)) * 8)] = u0;
      *(u16x8*)&sA[r * 64 + (((c0 + 1) ^ (r & 7)) * 8)] = u1;
    }
    // stage B: 192x64 bf16 from WT (L2-resident)
    #pragma unroll
    for (int it = 0; it < 12; ++it) {
      const int cid = it * 128 + tid;    // 1536 chunks of 8 bf16
      const int n = cid >> 3;
      const int c = cid & 7;
      const u16x8 v = *(const u16x8*)(wt + (size_t)n * NC + k0 + c * 8);
      *(u16x8*)&sB[n * 64 + ((c ^ (n & 7)) * 8)] = v;
    }
    __syncthreads();
    #pragma unroll
    for (int ks = 0; ks < 2; ++ks) {
      const int ar = w * 16 + li;
      const bf16x8 a = *(const bf16x8*)&sA[ar * 64 + (((ks * 4 + g) ^ (ar & 7)) * 8)];
      #pragma unroll
      for (int fn = 0; fn < 12; ++fn) {
        const int n = fn * 16 + li;
        const bf16x8 b = *(const bf16x8*)&sB[n * 64 + (((ks * 4 + g) ^ (n & 7)) * 8)];
        acc[fn] = __builtin_amdgcn_mfma_f32_16x16x32_bf16(a, b, acc[fn], 0, 0, 0);
      }
    }
    __syncthreads();
  }

  // epilogue: C/D layout col=lane&15, row=(lane>>4)*4+reg
  const int rr0 = row0 + w * 16 + g * 4;
  #pragma unroll
  for (int fn = 0; fn < 4; ++fn) {
    #pragma unroll
    for (int i = 0; i < 4; ++i) {
      qo[(size_t)(rr0 + i) * NH + fn * 16 + li] = f2b(acc[fn][i]);
      ko[(size_t)(rr0 + i) * NH + fn * 16 + li] = f2b(acc[4 + fn][i]);
    }
    u16x4 pv;
    #pragma unroll
    for (int i = 0; i < 4; ++i) pv[i] = f2b(acc[8 + fn][i]);
    const int hs = fn * 16 + li;
    const int bidx = rr0 >> 11;
    const int tt = rr0 & 2047;
    *(u16x4*)&vto[((size_t)(bidx * 64 + hs)) * NT + tt] = pv;
  }
}

// ---------------- flash-style causal attention
// grid (32, 4): pair j -> q-tiles j and 63-j (uniform work); 2 waves x 16 q-rows; KVBLK=64
__global__ __launch_bounds__(128) void attn_kernel(const u16* __restrict__ qg,
                                                   const u16* __restrict__ kg,
                                                   const u16* __restrict__ vtg,
                                                   float* __restrict__ out) {
  __shared__ u16 sK[64 * 64];       // [kv][hs] swizzled
  __shared__ u16 sV[64 * 64];       // [hs][kv] swizzled (V stored transposed in ws)
  __shared__ u16 sP[2][16 * 64];    // per-wave P tile [q][kv] swizzled
  const int tid = threadIdx.x;
  const int lane = tid & 63;
  const int w = tid >> 6;
  const int g = lane >> 4;
  const int li = lane & 15;
  const int bb = blockIdx.y;
  const size_t bt0 = (size_t)bb * NT;

  for (int pass = 0; pass < 2; ++pass) {
    const int jt = pass ? (63 - (int)blockIdx.x) : (int)blockIdx.x;
    const int q0 = jt * 32;
    const int q0w = q0 + w * 16;

    bf16x8 aq[2];
    #pragma unroll
    for (int ks = 0; ks < 2; ++ks)
      aq[ks] = *(const bf16x8*)(qg + (bt0 + q0w + li) * NH + ks * 32 + g * 8);

    const f32x4 zero = {0.f, 0.f, 0.f, 0.f};
    f32x4 o[4];
    float mrow[4], lrow[4];
    #pragma unroll
    for (int i = 0; i < 4; ++i) { o[i] = zero; mrow[i] = -1e30f; lrow[i] = 0.f; }

    const int nkv = jt / 2 + 1;
    for (int t = 0; t < nkv; ++t) {
      const int kv0 = t * 64;
      // stage K and V^T tiles (512 chunks each of 16B)
      #pragma unroll
      for (int it = 0; it < 4; ++it) {
        const int cid = it * 128 + tid;
        const int n = cid >> 3;
        const int c = cid & 7;
        const u16x8 vk = *(const u16x8*)(kg + (bt0 + kv0 + n) * NH + c * 8);
        *(u16x8*)&sK[n * 64 + ((c ^ (n & 7)) * 8)] = vk;
        const u16x8 vv = *(const u16x8*)(vtg + ((size_t)(bb * 64 + n)) * NT + kv0 + c * 8);
        *(u16x8*)&sV[n * 64 + ((c ^ (n & 7)) * 8)] = vv;
      }
      __syncthreads();

      // S = Q K^T  (S[q][kv], q rows held per reg, kv across lanes)
      f32x4 s[4];
      #pragma unroll
      for (int fn = 0; fn < 4; ++fn) s[fn] = zero;
      #pragma unroll
      for (int ks = 0; ks < 2; ++ks) {
        #pragma unroll
        for (int fn = 0; fn < 4; ++fn) {
          const int n = fn * 16 + li;
          const bf16x8 bk = *(const bf16x8*)&sK[n * 64 + (((ks * 4 + g) ^ (n & 7)) * 8)];
          s[fn] = __builtin_amdgcn_mfma_f32_16x16x32_bf16(aq[ks], bk, s[fn], 0, 0, 0);
        }
      }

      // scale + causal mask + online softmax (row = 16-lane group, shfl_xor 1/2/4/8)
      float p[4][4];
      const bool needmask = (kv0 + 63 > q0w);
      #pragma unroll
      for (int fn = 0; fn < 4; ++fn) {
        #pragma unroll
        for (int i = 0; i < 4; ++i) {
          float v = s[fn][i] * 0.125f;
          if (needmask && (kv0 + fn * 16 + li > q0w + g * 4 + i)) v = -1e30f;
          p[fn][i] = v;
        }
      }
      #pragma unroll
      for (int i = 0; i < 4; ++i) {
        float tm = fmaxf(fmaxf(p[0][i], p[1][i]), fmaxf(p[2][i], p[3][i]));
        tm = fmaxf(tm, __shfl_xor(tm, 1));
        tm = fmaxf(tm, __shfl_xor(tm, 2));
        tm = fmaxf(tm, __shfl_xor(tm, 4));
        tm = fmaxf(tm, __shfl_xor(tm, 8));
        const float newm = fmaxf(mrow[i], tm);
        const float scold = __expf(mrow[i] - newm);
        mrow[i] = newm;
        float rs = 0.f;
        #pragma unroll
        for (int fn = 0; fn < 4; ++fn) {
          const float e = __expf(p[fn][i] - newm);
          p[fn][i] = e;
          rs += e;
        }
        rs += __shfl_xor(rs, 1);
        rs += __shfl_xor(rs, 2);
        rs += __shfl_xor(rs, 4);
        rs += __shfl_xor(rs, 8);
        lrow[i] = lrow[i] * scold + rs;
        #pragma unroll
        for (int fn = 0; fn < 4; ++fn) o[fn][i] *= scold;
      }

      // P (bf16) -> per-wave LDS tile in A-fragment-friendly swizzled layout
      #pragma unroll
      for (int fn = 0; fn < 4; ++fn) {
        #pragma unroll
        for (int i = 0; i < 4; ++i) {
          const int ql = g * 4 + i;
          const int kv = fn * 16 + li;
          sP[w][ql * 64 + (((kv >> 3) ^ (ql & 7)) * 8) + (kv & 7)] = f2b(p[fn][i]);
        }
      }
      // O += P V
      #pragma unroll
      for (int ks = 0; ks < 2; ++ks) {
        const bf16x8 pa = *(const bf16x8*)&sP[w][li * 64 + (((ks * 4 + g) ^ (li & 7)) * 8)];
        #pragma unroll
        for (int fn = 0; fn < 4; ++fn) {
          const int n = fn * 16 + li;
          const bf16x8 bv = *(const bf16x8*)&sV[n * 64 + (((ks * 4 + g) ^ (n & 7)) * 8)];
          o[fn] = __builtin_amdgcn_mfma_f32_16x16x32_bf16(pa, bv, o[fn], 0, 0, 0);
        }
      }
      __syncthreads();
    }

    // epilogue: normalize and write fp32
    #pragma unroll
    for (int fn = 0; fn < 4; ++fn) {
      #pragma unroll
      for (int i = 0; i < 4; ++i) {
        out[(bt0 + q0w + g * 4 + i) * NH + fn * 16 + li] = o[fn][i] / lrow[i];
      }
    }
  }
}

extern "C" void kernel_launch(void* const* d_in, const int* in_sizes, int n_in,
                              void* d_out, int out_size, void* d_ws, size_t ws_size,
                              hipStream_t stream) {
  (void)in_sizes; (void)n_in; (void)out_size; (void)ws_size;
  const float* x  = (const float*)d_in[0];
  const float* Wq = (const float*)d_in[1];
  const float* Wk = (const float*)d_in[2];
  const float* Wv = (const float*)d_in[3];
  float* out = (float*)d_out;
  char* ws = (char*)d_ws;
  u16* qb  = (u16*)(ws);                    // 1 MB  : q bf16 [8192][64]
  u16* kb  = (u16*)(ws + (1u << 20));       // 1 MB  : k bf16 [8192][64]
  u16* vtb = (u16*)(ws + (2u << 20));       // 1 MB  : v^T bf16 [4][64][2048]
  u16* wtb = (u16*)(ws + (3u << 20));       // 384 KB: WT bf16 [3][64][1024]
  hipLaunchKernelGGL(wt_kernel,   dim3(192),   dim3(256), 0, stream, Wq, Wk, Wv, wtb);
  hipLaunchKernelGGL(proj_kernel, dim3(256),   dim3(128), 0, stream, x, wtb, qb, kb, vtb);
  hipLaunchKernelGGL(attn_kernel, dim3(32, 4), dim3(128), 0, stream, qb, kb, vtb, out);
}

// Round 2
// 62.806 us; speedup vs baseline: 1.4599x; 1.4599x over previous
//
#include <hip/hip_runtime.h>
#include <stdint.h>

#define NB 4
#define NT 2048
#define NC 1024
#define NH 64
#define NM (NB*NT)

typedef unsigned short u16;
typedef __bf16 bf16_t;
typedef float f32x4 __attribute__((ext_vector_type(4)));
typedef bf16_t bf16x8 __attribute__((ext_vector_type(8)));
typedef u16 u16x8 __attribute__((ext_vector_type(8)));
typedef u16 u16x4 __attribute__((ext_vector_type(4)));

__device__ __forceinline__ u16 f2b(float f) {
  return __builtin_bit_cast(u16, (bf16_t)f);
}

// ---------------- Wq/Wk/Wv [1024][64] f32 -> WT [3][64][1024] bf16 (transposed)
// coalesced reads + LDS transpose; grid 48 = 3 mats x 16 k-chunks
__global__ __launch_bounds__(256) void wt_kernel(const float* __restrict__ Wq,
                                                 const float* __restrict__ Wk,
                                                 const float* __restrict__ Wv,
                                                 u16* __restrict__ wt) {
  __shared__ float t[64][65];
  const int m = blockIdx.x >> 4;
  const int kt = blockIdx.x & 15;
  const int k0 = kt * 64;
  const float* W = (m == 0) ? Wq : (m == 1) ? Wk : Wv;
  {
    const int r = threadIdx.x >> 2, c4 = threadIdx.x & 3;
    #pragma unroll
    for (int j = 0; j < 4; ++j) {
      const float4 f = *(const float4*)(W + (size_t)(k0 + r) * NH + c4 * 16 + j * 4);
      t[r][c4 * 16 + j * 4 + 0] = f.x;
      t[r][c4 * 16 + j * 4 + 1] = f.y;
      t[r][c4 * 16 + j * 4 + 2] = f.z;
      t[r][c4 * 16 + j * 4 + 3] = f.w;
    }
  }
  __syncthreads();
  const int n = threadIdx.x >> 2, kc = threadIdx.x & 3;
  u16x8 a, b;
  #pragma unroll
  for (int j = 0; j < 8; ++j) a[j] = f2b(t[kc * 16 + j][n]);
  #pragma unroll
  for (int j = 0; j < 8; ++j) b[j] = f2b(t[kc * 16 + 8 + j][n]);
  u16* dst = wt + ((size_t)(m * 64 + n)) * NC + k0 + kc * 16;
  *(u16x8*)dst = a;
  *(u16x8*)(dst + 8) = b;
}

// ---------------- fused QKV projection: x[8192][1024] f32 @ WT -> q,k bf16 [8192][64], vt bf16 [4][64][2048]
// 4 waves: 2 row-subtiles x 2 N-halves
__global__ __launch_bounds__(256) void proj_kernel(const float* __restrict__ x,
                                                   const u16* __restrict__ wt,
                                                   u16* __restrict__ qo,
                                                   u16* __restrict__ ko,
                                                   u16* __restrict__ vto) {
  __shared__ u16 sA[32 * 64];    // [row][k] bf16, 16B-chunk XOR swizzle
  __shared__ u16 sB[192 * 64];   // [n][k] bf16, same swizzle
  const int tid = threadIdx.x;
  const int lane = tid & 63;
  const int wv = tid >> 6;       // 0..3
  const int w = wv & 1;          // row subtile
  const int h = wv >> 1;         // n half
  const int g = lane >> 4;
  const int li = lane & 15;
  const int row0 = blockIdx.x * 32;

  const f32x4 zero = {0.f, 0.f, 0.f, 0.f};
  f32x4 acc[6];
  #pragma unroll
  for (int i = 0; i < 6; ++i) acc[i] = zero;

  const int r = tid >> 3;        // 0..31 staging row
  const int fc = tid & 7;        // 8-float chunk within row
  const float* xsrc = x + (size_t)(row0 + r) * NC + fc * 8;

  for (int kt = 0; kt < 16; ++kt) {
    const int k0 = kt * 64;
    // stage A: 32x64 fp32 -> bf16
    {
      const float4 f0 = *(const float4*)(xsrc + k0);
      const float4 f1 = *(const float4*)(xsrc + k0 + 4);
      u16x8 u0;
      u0[0]=f2b(f0.x); u0[1]=f2b(f0.y); u0[2]=f2b(f0.z); u0[3]=f2b(f0.w);
      u0[4]=f2b(f1.x); u0[5]=f2b(f1.y); u0[6]=f2b(f1.z); u0[7]=f2b(f1.w);
      *(u16x8*)&sA[r * 64 + ((fc ^ (r & 7)) * 8)] = u0;
    }
    // stage B: 192x64 bf16 from WT (L2-resident)
    #pragma unroll
    for (int it = 0; it < 6; ++it) {
      const int cid = it * 256 + tid;    // 1536 chunks of 8 bf16
      const int n = cid >> 3;
      const int c = cid & 7;
      const u16x8 v = *(const u16x8*)(wt + (size_t)n * NC + k0 + c * 8);
      *(u16x8*)&sB[n * 64 + ((c ^ (n & 7)) * 8)] = v;
    }
    __syncthreads();
    #pragma unroll
    for (int ks = 0; ks < 2; ++ks) {
      const int ar = w * 16 + li;
      const bf16x8 a = *(const bf16x8*)&sA[ar * 64 + (((ks * 4 + g) ^ (ar & 7)) * 8)];
      #pragma unroll
      for (int fn6 = 0; fn6 < 6; ++fn6) {
        const int n = (h * 6 + fn6) * 16 + li;
        const bf16x8 b = *(const bf16x8*)&sB[n * 64 + (((ks * 4 + g) ^ (n & 7)) * 8)];
        acc[fn6] = __builtin_amdgcn_mfma_f32_16x16x32_bf16(a, b, acc[fn6], 0, 0, 0);
      }
    }
    __syncthreads();
  }

  // epilogue: C/D layout col=lane&15, row=(lane>>4)*4+reg
  const int rr0 = row0 + w * 16 + g * 4;
  #pragma unroll
  for (int fn6 = 0; fn6 < 6; ++fn6) {
    const int fn = h * 6 + fn6;
    if (fn < 4) {
      #pragma unroll
      for (int i = 0; i < 4; ++i)
        qo[(size_t)(rr0 + i) * NH + fn * 16 + li] = f2b(acc[fn6][i]);
    } else if (fn < 8) {
      #pragma unroll
      for (int i = 0; i < 4; ++i)
        ko[(size_t)(rr0 + i) * NH + (fn - 4) * 16 + li] = f2b(acc[fn6][i]);
    } else {
      u16x4 pv;
      #pragma unroll
      for (int i = 0; i < 4; ++i) pv[i] = f2b(acc[fn6][i]);
      const int hs = (fn - 8) * 16 + li;
      const int bidx = rr0 >> 11;
      const int tt = rr0 & 2047;
      *(u16x4*)&vto[((size_t)(bidx * 64 + hs)) * NT + tt] = pv;
    }
  }
}

// ---------------- flash-style causal attention, intra-block KV split
// grid (64, 4): one 32-row q-tile per block; 8 waves = 4 kv-splits x 2 q-subwaves
union AttnShm {
  struct { u16 K[4][4096]; u16 V[4][4096]; } st;                 // 64 KB staging
  struct { float po[4][2][16][68]; float pml[4][2][16][2]; } mg; // merge buffers (aliased)
};

__global__ __launch_bounds__(512) void attn_kernel(const u16* __restrict__ qg,
                                                   const u16* __restrict__ kg,
                                                   const u16* __restrict__ vtg,
                                                   float* __restrict__ out) {
  __shared__ AttnShm shm;
  __shared__ u16 sP[8][16 * 64];   // per-wave P tile [q][kv] swizzled
  const int tid = threadIdx.x;
  const int lane = tid & 63;
  const int wv = tid >> 6;         // 0..7
  const int s = wv >> 1;           // kv split 0..3
  const int w = wv & 1;            // q subtile
  const int g = lane >> 4;
  const int li = lane & 15;
  const int jt = blockIdx.x;
  const int bb = blockIdx.y;
  const size_t bt0 = (size_t)bb * NT;
  const int q0w = jt * 32 + w * 16;
  const int gtid = w * 64 + lane;  // 0..127 within kv-split group

  bf16x8 aq[2];
  #pragma unroll
  for (int ks = 0; ks < 2; ++ks)
    aq[ks] = *(const bf16x8*)(qg + (bt0 + q0w + li) * NH + ks * 32 + g * 8);

  const f32x4 zero = {0.f, 0.f, 0.f, 0.f};
  f32x4 o[4];
  float mrow[4], lrow[4];
  #pragma unroll
  for (int i = 0; i < 4; ++i) { o[i] = zero; mrow[i] = -1e30f; lrow[i] = 0.f; }

  const int nkv = jt / 2 + 1;
  const int tmax = (nkv + 3) >> 2;
  u16* myK = shm.st.K[s];
  u16* myV = shm.st.V[s];

  for (int tt = 0; tt < tmax; ++tt) {
    const int t = tt * 4 + s;
    const bool act = (t < nkv);
    const int kv0 = t * 64;
    if (act) {
      #pragma unroll
      for (int it = 0; it < 4; ++it) {
        const int cid = it * 128 + gtid;
        const int n = cid >> 3;
        const int c = cid & 7;
        const u16x8 vk = *(const u16x8*)(kg + (bt0 + kv0 + n) * NH + c * 8);
        *(u16x8*)&myK[n * 64 + ((c ^ (n & 7)) * 8)] = vk;
        const u16x8 vv = *(const u16x8*)(vtg + ((size_t)(bb * 64 + n)) * NT + kv0 + c * 8);
        *(u16x8*)&myV[n * 64 + ((c ^ (n & 7)) * 8)] = vv;
      }
    }
    __syncthreads();
    if (act) {
      // S = Q K^T
      f32x4 sc[4];
      #pragma unroll
      for (int fn = 0; fn < 4; ++fn) sc[fn] = zero;
      #pragma unroll
      for (int ks = 0; ks < 2; ++ks) {
        #pragma unroll
        for (int fn = 0; fn < 4; ++fn) {
          const int n = fn * 16 + li;
          const bf16x8 bk = *(const bf16x8*)&myK[n * 64 + (((ks * 4 + g) ^ (n & 7)) * 8)];
          sc[fn] = __builtin_amdgcn_mfma_f32_16x16x32_bf16(aq[ks], bk, sc[fn], 0, 0, 0);
        }
      }

      // scale + causal mask + online softmax (row = 16-lane group)
      float p[4][4];
      const bool needmask = (kv0 + 63 > q0w);
      #pragma unroll
      for (int fn = 0; fn < 4; ++fn) {
        #pragma unroll
        for (int i = 0; i < 4; ++i) {
          float v = sc[fn][i] * 0.125f;
          if (needmask && (kv0 + fn * 16 + li > q0w + g * 4 + i)) v = -1e30f;
          p[fn][i] = v;
        }
      }
      #pragma unroll
      for (int i = 0; i < 4; ++i) {
        float tm = fmaxf(fmaxf(p[0][i], p[1][i]), fmaxf(p[2][i], p[3][i]));
        tm = fmaxf(tm, __shfl_xor(tm, 1));
        tm = fmaxf(tm, __shfl_xor(tm, 2));
        tm = fmaxf(tm, __shfl_xor(tm, 4));
        tm = fmaxf(tm, __shfl_xor(tm, 8));
        const float newm = fmaxf(mrow[i], tm);
        const float scold = __expf(mrow[i] - newm);
        mrow[i] = newm;
        float rs = 0.f;
        #pragma unroll
        for (int fn = 0; fn < 4; ++fn) {
          const float e = __expf(p[fn][i] - newm);
          p[fn][i] = e;
          rs += e;
        }
        rs += __shfl_xor(rs, 1);
        rs += __shfl_xor(rs, 2);
        rs += __shfl_xor(rs, 4);
        rs += __shfl_xor(rs, 8);
        lrow[i] = lrow[i] * scold + rs;
        #pragma unroll
        for (int fn = 0; fn < 4; ++fn) o[fn][i] *= scold;
      }

      // P (bf16) -> per-wave LDS tile in A-fragment layout
      #pragma unroll
      for (int fn = 0; fn < 4; ++fn) {
        #pragma unroll
        for (int i = 0; i < 4; ++i) {
          const int ql = g * 4 + i;
          const int kv = fn * 16 + li;
          sP[wv][ql * 64 + (((kv >> 3) ^ (ql & 7)) * 8) + (kv & 7)] = f2b(p[fn][i]);
        }
      }
      // O += P V
      #pragma unroll
      for (int ks = 0; ks < 2; ++ks) {
        const bf16x8 pa = *(const bf16x8*)&sP[wv][li * 64 + (((ks * 4 + g) ^ (li & 7)) * 8)];
        #pragma unroll
        for (int fn = 0; fn < 4; ++fn) {
          const int n = fn * 16 + li;
          const bf16x8 bv = *(const bf16x8*)&myV[n * 64 + (((ks * 4 + g) ^ (n & 7)) * 8)];
          o[fn] = __builtin_amdgcn_mfma_f32_16x16x32_bf16(pa, bv, o[fn], 0, 0, 0);
        }
      }
    }
    __syncthreads();
  }

  // ---- merge 4 kv-splits (aliases the staging LDS; all compute is behind the barrier)
  #pragma unroll
  for (int fn = 0; fn < 4; ++fn)
    #pragma unroll
    for (int i = 0; i < 4; ++i)
      shm.mg.po[s][w][g * 4 + i][fn * 16 + li] = o[fn][i];
  if (li == 0) {
    #pragma unroll
    for (int i = 0; i < 4; ++i) {
      shm.mg.pml[s][w][g * 4 + i][0] = mrow[i];
      shm.mg.pml[s][w][g * 4 + i][1] = lrow[i];
    }
  }
  __syncthreads();
  if (s == 0) {
    float es[4][4], Li[4];
    #pragma unroll
    for (int i = 0; i < 4; ++i) {
      const int row = g * 4 + i;
      float M = shm.mg.pml[0][w][row][0];
      #pragma unroll
      for (int s4 = 1; s4 < 4; ++s4) M = fmaxf(M, shm.mg.pml[s4][w][row][0]);
      float L = 0.f;
      #pragma unroll
      for (int s4 = 0; s4 < 4; ++s4) {
        const float e = __expf(shm.mg.pml[s4][w][row][0] - M);
        es[i][s4] = e;
        L += shm.mg.pml[s4][w][row][1] * e;
      }
      Li[i] = L;
    }
    #pragma unroll
    for (int fn = 0; fn < 4; ++fn) {
      #pragma unroll
      for (int i = 0; i < 4; ++i) {
        float acc = 0.f;
        #pragma unroll
        for (int s4 = 0; s4 < 4; ++s4)
          acc += shm.mg.po[s4][w][g * 4 + i][fn * 16 + li] * es[i][s4];
        out[(bt0 + q0w + g * 4 + i) * NH + fn * 16 + li] = acc / Li[i];
      }
    }
  }
}

extern "C" void kernel_launch(void* const* d_in, const int* in_sizes, int n_in,
                              void* d_out, int out_size, void* d_ws, size_t ws_size,
                              hipStream_t stream) {
  (void)in_sizes; (void)n_in; (void)out_size; (void)ws_size;
  const float* x  = (const float*)d_in[0];
  const float* Wq = (const float*)d_in[1];
  const float* Wk = (const float*)d_in[2];
  const float* Wv = (const float*)d_in[3];
  float* out = (float*)d_out;
  char* ws = (char*)d_ws;
  u16* qb  = (u16*)(ws);                    // 1 MB  : q bf16 [8192][64]
  u16* kb  = (u16*)(ws + (1u << 20));       // 1 MB  : k bf16 [8192][64]
  u16* vtb = (u16*)(ws + (2u << 20));       // 1 MB  : v^T bf16 [4][64][2048]
  u16* wtb = (u16*)(ws + (3u << 20));       // 384 KB: WT bf16 [3][64][1024]
  hipLaunchKernelGGL(wt_kernel,   dim3(48),    dim3(256), 0, stream, Wq, Wk, Wv, wtb);
  hipLaunchKernelGGL(proj_kernel, dim3(256),   dim3(256), 0, stream, x, wtb, qb, kb, vtb);
  hipLaunchKernelGGL(attn_kernel, dim3(64, 4), dim3(512), 0, stream, qb, kb, vtb, out);
}